// Round 11
// baseline (693.002 us; speedup 1.0000x reference)
//
#include <hip/hip_runtime.h>
#include <cstddef>

// K-Planes field eval: 4 scales x 3 planes bilinear sample (32ch), 3-way
// product per scale -> 128 feats -> MLP 128->64->64->1 (ReLU, bias-free).
//
// R11 strategy (fused kernel = R10, unchanged):
//  - transpose vectorized (float4 in, uint4 out) + hist MERGED into its grid
//  - scan: 256x1024 local scans + last-block ticket does 256-wide bsum scan
//      in-LDS; block 0 also does weight prep  (launches 7 -> 5)
//  - sort refined to 6 bits/axis (262144 buckets, ~4 pts/bucket) -> less
//      L2 re-fetch; scatter recomputes key (key16 cache dropped)

typedef unsigned short ushort_t;
typedef unsigned int uint_t;
typedef __bf16 bf16x8 __attribute__((ext_vector_type(8)));
typedef float f32x4 __attribute__((ext_vector_type(4)));

#define NBUCKET 262144
#define NTRANSP 65280  // 21760 tiles x 3 planes

struct KParams {
  const float* x;
  const void* g[12];
  const float* w0;
  const float* w1;
  const float* w2;
  const ushort_t* w0T;  // [64 n][128 k] bf16
  const ushort_t* w1T;  // [64 n][64 k]  bf16
  const float* xs;      // sorted points [N][3]
  const int* sidx;      // sorted -> original index
  float* out;
  int N;
};

struct TPA {
  const float* src[12];
  ushort_t* dst[12];
};

__device__ __forceinline__ ushort_t f32_to_bf16_rne(float f) {
  uint_t u = __float_as_uint(f);
  u = (u + 0x7FFFu + ((u >> 16) & 1u)) >> 16;
  return (ushort_t)u;
}

__device__ __forceinline__ uint_t spread6(uint_t v) {
  return (v & 1u) | ((v & 2u) << 2) | ((v & 4u) << 4) | ((v & 8u) << 6) |
         ((v & 16u) << 8) | ((v & 32u) << 10);
}
__device__ __forceinline__ uint_t morton_key(const float* __restrict__ x,
                                             int i) {
  const float a = x[3 * i + 0];
  const float b = x[3 * i + 1];
  const float c = x[3 * i + 2];
  const uint_t ua = (uint_t)fminf(fmaxf((a + 1.0f) * 32.0f, 0.0f), 63.0f);
  const uint_t ub = (uint_t)fminf(fmaxf((b + 1.0f) * 32.0f, 0.0f), 63.0f);
  const uint_t uc = (uint_t)fminf(fmaxf((c + 1.0f) * 32.0f, 0.0f), 63.0f);
  return spread6(ua) | (spread6(ub) << 1) | (spread6(uc) << 2);
}

// blocks [0,NTRANSP): transpose [32][RR] f32 -> [RR][32] bf16 (vectorized)
// blocks [NTRANSP, ...): Morton histogram (cnt may be null -> host omits blocks)
__global__ __launch_bounds__(256) void front_transpose_hist(
    TPA tp, const float* __restrict__ x, uint_t* __restrict__ cnt, int N) {
  const int b = blockIdx.x;
  const int t = threadIdx.x;
  if (b >= NTRANSP) {
    const int i = (b - NTRANSP) * 256 + t;
    if (i < N) atomicAdd(&cnt[morton_key(x, i)], 1u);
    return;
  }
  const int v = b / 3;
  const int pl = b - v * 3;
  int s, tile;
  if (v < 256) { s = 0; tile = v; }
  else if (v < 1280) { s = 1; tile = v - 256; }
  else if (v < 5376) { s = 2; tile = v - 1280; }
  else { s = 3; tile = v - 5376; }
  const int RR = 16384 << (2 * s);
  const int k = s * 3 + pl;
  const float* __restrict__ in = tp.src[k];
  ushort_t* __restrict__ out = tp.dst[k];

  __shared__ float tile_s[32][68];  // stride 68 dw: 16B-aligned rows
  const int p0 = tile * 64;
  // read: 512 float4 (2/thread), coalesced rows
#pragma unroll
  for (int it = 0; it < 2; ++it) {
    const int idx = it * 256 + t;
    const int row = idx >> 4;
    const int qc = idx & 15;
    const float4 vv = *(const float4*)(in + (size_t)row * RR + p0 + qc * 4);
    *(float4*)&tile_s[row][qc * 4] = vv;
  }
  __syncthreads();
  // write: 256 uint4 (1/thread), coalesced
  const int pos = t >> 2;  // 0..63
  const int cq = t & 3;    // channels [cq*8, cq*8+8)
  uint4 dv;
  {
    uint_t d[4];
#pragma unroll
    for (int h = 0; h < 4; ++h) {
      const uint_t lo = f32_to_bf16_rne(tile_s[cq * 8 + 2 * h + 0][pos]);
      const uint_t hi = f32_to_bf16_rne(tile_s[cq * 8 + 2 * h + 1][pos]);
      d[h] = lo | (hi << 16);
    }
    dv.x = d[0]; dv.y = d[1]; dv.z = d[2]; dv.w = d[3];
  }
  *(uint4*)((uint_t*)out + (size_t)(p0 + pos) * 16 + cq * 4) = dv;
}

// standalone weight prep (non-sorted fallback path)
__global__ __launch_bounds__(256) void prep_weights(
    const float* __restrict__ w0, const float* __restrict__ w1,
    ushort_t* __restrict__ w0T, ushort_t* __restrict__ w1T) {
  const int t = threadIdx.x;
  for (int i = t; i < 128 * 64; i += 256) {
    const int k = i >> 6, n = i & 63;
    w0T[n * 128 + k] = f32_to_bf16_rne(w0[i]);
  }
  for (int i = t; i < 64 * 64; i += 256) {
    const int k = i >> 6, n = i & 63;
    w1T[n * 64 + k] = f32_to_bf16_rne(w1[i]);
  }
}

// 256 blocks x 1024: local scan; last block (ticket) scans bsum in LDS.
// block 0 also converts/transposes the MLP weights.
__global__ __launch_bounds__(1024) void sort_scan_prepw(
    uint_t* __restrict__ cnt, uint_t* __restrict__ bsum,
    uint_t* __restrict__ done, const float* __restrict__ w0,
    const float* __restrict__ w1, ushort_t* __restrict__ w0T,
    ushort_t* __restrict__ w1T) {
  __shared__ uint_t s[1024];
  __shared__ uint_t ticket;
  const int t = threadIdx.x;
  const int bidx = blockIdx.x;

  if (bidx == 0) {  // weight prep (independent, cheap)
    for (int i = t; i < 128 * 64; i += 1024) {
      const int k = i >> 6, n = i & 63;
      w0T[n * 128 + k] = f32_to_bf16_rne(w0[i]);
    }
    for (int i = t; i < 64 * 64; i += 1024) {
      const int k = i >> 6, n = i & 63;
      w1T[n * 64 + k] = f32_to_bf16_rne(w1[i]);
    }
  }

  const int idx = bidx * 1024 + t;
  const uint_t v = cnt[idx];
  s[t] = v;
  __syncthreads();
  for (int off = 1; off < 1024; off <<= 1) {
    uint_t u = 0;
    if (t >= off) u = s[t - off];
    __syncthreads();
    s[t] += u;
    __syncthreads();
  }
  cnt[idx] = s[t] - v;  // local exclusive
  if (t == 1023) bsum[bidx] = s[t];

  __threadfence();
  if (t == 0) ticket = atomicAdd(done, 1u);
  __syncthreads();
  if (ticket == 255) {  // last block: 256-wide exclusive scan of bsum
    __threadfence();
    uint_t bv = 0;
    if (t < 256) bv = bsum[t];
    s[t] = bv;
    __syncthreads();
    for (int off = 1; off < 256; off <<= 1) {
      uint_t u = 0;
      if (t >= off && t < 256) u = s[t - off];
      __syncthreads();
      if (t < 256) s[t] += u;
      __syncthreads();
    }
    if (t < 256) bsum[t] = s[t] - bv;
  }
}

__global__ __launch_bounds__(256) void sort_scatter(
    const float* __restrict__ x, uint_t* __restrict__ cnt,
    const uint_t* __restrict__ bsum, int* __restrict__ sidx,
    float* __restrict__ xs, int N) {
  const int i = blockIdx.x * 256 + threadIdx.x;
  if (i >= N) return;
  const uint_t key = morton_key(x, i);
  const uint_t pos = atomicAdd(&cnt[key], 1u) + bsum[key >> 10];
  sidx[pos] = i;
  xs[3 * pos + 0] = x[3 * i + 0];
  xs[3 * pos + 1] = x[3 * i + 1];
  xs[3 * pos + 2] = x[3 * i + 2];
}

// ---------------- fused sample + MFMA MLP (R10, unchanged) ----------------
template <bool SORTED>
__global__ __launch_bounds__(512, 6) void kplanes_fused_mfma(KParams P) {
  __shared__ float arena[8704];
  int4* o4s = (int4*)arena;
  float* wxs = arena + 3072;
  float* wys = arena + 3840;
  uint_t* feat32 = (uint_t*)(arena + 4608);
  float* px = arena + 4608;

  const int t = threadIdx.x;

  int bid = blockIdx.x;
  if (SORTED) {
    const int nblk = gridDim.x;
    const int q = nblk >> 3, r = nblk & 7;
    const int xcd = bid & 7, idx = bid >> 3;
    bid = (xcd < r ? xcd * (q + 1) : r * (q + 1) + (xcd - r) * q) + idx;
  }
  const int blk0 = bid * 64;

  if (SORTED) {
    if (t < 192) {
      int idx = blk0 * 3 + t;
      if (idx >= 3 * P.N) idx = 3 * P.N - 3 + (t % 3);
      px[t] = P.xs[idx];
    }
  } else {
    if (t < 192) {
      const int p = t / 3, e = t - p * 3;
      int Pi = blk0 + p;
      if (Pi >= P.N) Pi = P.N - 1;
      px[t] = P.x[3 * Pi + e];
    }
  }
  __syncthreads();

  for (int task = t; task < 768; task += 512) {
    const int pt = task & 63;
    const int sm = task >> 6;
    const int pl = sm >> 2;
    const int s = sm & 3;
    const float cx = (pl == 2) ? px[pt * 3 + 1] : px[pt * 3 + 0];
    const float cy = (pl == 0) ? px[pt * 3 + 1] : px[pt * 3 + 2];
    const int R = 128 << s;
    const float Rm1 = (float)(R - 1);
    const float u = fminf(fmaxf((cx + 1.0f) * 0.5f * Rm1, 0.0f), Rm1);
    const float v = fminf(fmaxf((cy + 1.0f) * 0.5f * Rm1, 0.0f), Rm1);
    const float fx0 = floorf(u), fy0 = floorf(v);
    const int x0 = (int)fx0, y0 = (int)fy0;
    const int x1 = min(x0 + 1, R - 1), y1 = min(y0 + 1, R - 1);
    int4 o4;
    o4.x = y0 * R + x0;
    o4.y = y0 * R + x1;
    o4.z = y1 * R + x0;
    o4.w = y1 * R + x1;
    o4s[task] = o4;
    wxs[task] = u - fx0;
    wys[task] = v - fy0;
  }
  __syncthreads();

  const int pt = t >> 3;
  const int q = t & 7;
  const int cg = q & 3;
  const int sh = q >> 2;
  uint_t* prow = feat32 + pt * 64;
  const int wxor = (pt & 7) << 2;

#define CBASE(st) (((((st) % 3) * 4) + (2 * ((st) / 3) + sh)) * 64 + pt)
#define GIDX(st) ((2 * ((st) / 3) + sh) * 3 + ((st) % 3))
#define ISSUE(O, GP, QA, QB, QC, QD)                              \
  QA = *(const uint4*)((GP) + (size_t)(O).x * 32 + cg * 8);       \
  QB = *(const uint4*)((GP) + (size_t)(O).y * 32 + cg * 8);       \
  QC = *(const uint4*)((GP) + (size_t)(O).z * 32 + cg * 8);       \
  QD = *(const uint4*)((GP) + (size_t)(O).w * 32 + cg * 8);
#define CH2(dA, dB, dC, dD, i0, i1)                                \
  {                                                                \
    float rl = __uint_as_float((dD) << 16) * w11;                  \
    rl = fmaf(__uint_as_float((dC) << 16), w10, rl);               \
    rl = fmaf(__uint_as_float((dB) << 16), w01, rl);               \
    rl = fmaf(__uint_as_float((dA) << 16), w00, rl);               \
    f[i0] *= rl;                                                   \
    float rh = __uint_as_float((dD)&0xFFFF0000u) * w11;            \
    rh = fmaf(__uint_as_float((dC)&0xFFFF0000u), w10, rh);         \
    rh = fmaf(__uint_as_float((dB)&0xFFFF0000u), w01, rh);         \
    rh = fmaf(__uint_as_float((dA)&0xFFFF0000u), w00, rh);         \
    f[i1] *= rh;                                                   \
  }

  {
    uint4 A, B, C, D, A2, B2, C2, D2;
    float wx_c, wy_c, wx_n, wy_n;
    float f[8];

    {
      const int b_ = CBASE(0);
      const int4 o = o4s[b_];
      wx_c = wxs[b_];
      wy_c = wys[b_];
      const ushort_t* gp = (const ushort_t*)P.g[GIDX(0)];
      ISSUE(o, gp, A, B, C, D)
    }

#pragma unroll
    for (int st = 0; st < 6; ++st) {
      if (st < 5) {
        const int b_ = CBASE(st + 1);
        const int4 o = o4s[b_];
        wx_n = wxs[b_];
        wy_n = wys[b_];
        const ushort_t* gp = (const ushort_t*)P.g[GIDX(st + 1)];
        ISSUE(o, gp, A2, B2, C2, D2)
      }
      if ((st % 3) == 0) {
#pragma unroll
        for (int c = 0; c < 8; ++c) f[c] = 1.0f;
      }
      {
        const float w11 = wx_c * wy_c;
        const float w10 = wy_c - w11;
        const float w01 = wx_c - w11;
        const float w00 = 1.0f - wx_c - w10;
        CH2(A.x, B.x, C.x, D.x, 0, 1)
        CH2(A.y, B.y, C.y, D.y, 2, 3)
        CH2(A.z, B.z, C.z, D.z, 4, 5)
        CH2(A.w, B.w, C.w, D.w, 6, 7)
      }
      if ((st % 3) == 2) {
        const int s = 2 * (st / 3) + sh;
        uint_t d0, d1, d2, d3;
        asm("v_cvt_pk_bf16_f32 %0, %1, %2" : "=v"(d0) : "v"(f[0]), "v"(f[1]));
        asm("v_cvt_pk_bf16_f32 %0, %1, %2" : "=v"(d1) : "v"(f[2]), "v"(f[3]));
        asm("v_cvt_pk_bf16_f32 %0, %1, %2" : "=v"(d2) : "v"(f[4]), "v"(f[5]));
        asm("v_cvt_pk_bf16_f32 %0, %1, %2" : "=v"(d3) : "v"(f[6]), "v"(f[7]));
        uint4 dv;
        dv.x = d0; dv.y = d1; dv.z = d2; dv.w = d3;
        *(uint4*)(prow + ((s * 16 + cg * 4) ^ wxor)) = dv;
      }
      A = A2; B = B2; C = C2; D = D2;
      wx_c = wx_n; wy_c = wy_n;
    }
  }
#undef CBASE
#undef GIDX
#undef ISSUE
#undef CH2
  __syncthreads();

  ushort_t* lds_h = (ushort_t*)arena;
  float(*oparts)[64] = (float(*)[64])(arena + 2048);

  const int w = __builtin_amdgcn_readfirstlane(t >> 6);
  const int mt = w & 3;
  const int nt0 = (w >> 2) << 1;
  const int ln = t & 15;
  const int lq = (t >> 4) & 3;
  const int arow = mt * 16 + ln;

  const uint_t* farow = feat32 + arow * 64;
  const int axor = (arow & 7) << 2;
  f32x4 acc0a = {0.f, 0.f, 0.f, 0.f}, acc0b = {0.f, 0.f, 0.f, 0.f};
  const ushort_t* w0a = P.w0T + (nt0 * 16 + ln) * 128 + lq * 8;
  const ushort_t* w0b = w0a + 16 * 128;
#pragma unroll
  for (int kt = 0; kt < 4; ++kt) {
    const bf16x8 aF = *(const bf16x8*)(farow + ((kt * 16 + lq * 4) ^ axor));
    const bf16x8 bFa = *(const bf16x8*)(w0a + kt * 32);
    const bf16x8 bFb = *(const bf16x8*)(w0b + kt * 32);
    acc0a = __builtin_amdgcn_mfma_f32_16x16x32_bf16(aF, bFa, acc0a, 0, 0, 0);
    acc0b = __builtin_amdgcn_mfma_f32_16x16x32_bf16(aF, bFb, acc0b, 0, 0, 0);
  }

#pragma unroll
  for (int i = 0; i < 2; ++i) {
    const f32x4 a = i ? acc0b : acc0a;
    const int col = (nt0 + i) * 16 + ln;
#pragma unroll
    for (int jj = 0; jj < 4; ++jj) {
      const float v = fmaxf(a[jj], 0.0f);
      uint_t dv;
      asm("v_cvt_pk_bf16_f32 %0, %1, %2" : "=v"(dv) : "v"(v), "v"(v));
      const int r = mt * 16 + lq * 4 + jj;
      lds_h[r * 64 + (col ^ ((r & 7) << 3))] = (ushort_t)dv;
    }
  }
  __syncthreads();

  const ushort_t* hrow = lds_h + arow * 64;
  const int hxor = (arow & 7) << 3;
  f32x4 acc1a = {0.f, 0.f, 0.f, 0.f}, acc1b = {0.f, 0.f, 0.f, 0.f};
  const ushort_t* w1a = P.w1T + (nt0 * 16 + ln) * 64 + lq * 8;
  const ushort_t* w1b = w1a + 16 * 64;
#pragma unroll
  for (int kt = 0; kt < 2; ++kt) {
    const bf16x8 aF = *(const bf16x8*)(hrow + ((kt * 32 + lq * 8) ^ hxor));
    const bf16x8 bFa = *(const bf16x8*)(w1a + kt * 32);
    const bf16x8 bFb = *(const bf16x8*)(w1b + kt * 32);
    acc1a = __builtin_amdgcn_mfma_f32_16x16x32_bf16(aF, bFa, acc1a, 0, 0, 0);
    acc1b = __builtin_amdgcn_mfma_f32_16x16x32_bf16(aF, bFb, acc1b, 0, 0, 0);
  }

  const float w2a = P.w2[nt0 * 16 + ln];
  const float w2b = P.w2[(nt0 + 1) * 16 + ln];
  float part[4];
#pragma unroll
  for (int jj = 0; jj < 4; ++jj)
    part[jj] = fmaxf(acc1a[jj], 0.f) * w2a + fmaxf(acc1b[jj], 0.f) * w2b;
#pragma unroll
  for (int jj = 0; jj < 4; ++jj) {
    part[jj] += __shfl_xor(part[jj], 1);
    part[jj] += __shfl_xor(part[jj], 2);
    part[jj] += __shfl_xor(part[jj], 4);
    part[jj] += __shfl_xor(part[jj], 8);
  }
  if (ln == 0) {
#pragma unroll
    for (int jj = 0; jj < 4; ++jj)
      oparts[w >> 2][mt * 16 + lq * 4 + jj] = part[jj];
  }
  __syncthreads();

  if (t < 64) {
    const int Po = blk0 + t;
    if (Po < P.N) {
      const float r = oparts[0][t] + oparts[1][t];
      if (SORTED)
        P.out[P.sidx[Po]] = r;
      else
        P.out[Po] = r;
    }
  }
}

// fallback (ws too small): f32 [C,H,W] grids, scalar MLP
__global__ __launch_bounds__(512, 8) void kplanes_fused_scalar(KParams P) {
  __shared__ float fl[64][130];
  const int t = threadIdx.x;
  const int pg = t >> 3;
  const int sub = t & 7;
  const int blk0 = blockIdx.x * 64;

  int Pi = blk0 + pg;
  if (Pi >= P.N) Pi = P.N - 1;
  const float c0 = P.x[3 * Pi + 0];
  const float c1 = P.x[3 * Pi + 1];
  const float c2 = P.x[3 * Pi + 2];

  float feat[4][4];
#pragma unroll
  for (int s = 0; s < 4; ++s)
#pragma unroll
    for (int c = 0; c < 4; ++c) feat[s][c] = 1.0f;

#pragma unroll
  for (int s = 0; s < 4; ++s) {
    const int R = 128 << s;
    const int RR = R * R;
#pragma unroll
    for (int pl = 0; pl < 3; ++pl) {
      const float cx = (pl == 2) ? c1 : c0;
      const float cy = (pl == 0) ? c1 : c2;
      const float Rm1 = (float)(R - 1);
      const float u = fminf(fmaxf((cx + 1.0f) * 0.5f * Rm1, 0.0f), Rm1);
      const float v = fminf(fmaxf((cy + 1.0f) * 0.5f * Rm1, 0.0f), Rm1);
      const float fx0 = floorf(u), fy0 = floorf(v);
      const float wx = u - fx0, wy = v - fy0;
      const int x0 = (int)fx0, y0 = (int)fy0;
      const int x1 = min(x0 + 1, R - 1), y1 = min(y0 + 1, R - 1);
      const float w11 = wx * wy;
      const float w10 = wy - w11;
      const float w01 = wx - w11;
      const float w00 = 1.0f - wx - w10;
      const float* gp = (const float*)P.g[s * 3 + pl];
      const int i00 = y0 * R + x0, i01 = y0 * R + x1;
      const int i10 = y1 * R + x0, i11 = y1 * R + x1;
#pragma unroll
      for (int c = 0; c < 4; ++c) {
        const size_t cb = (size_t)(sub * 4 + c) * RR;
        feat[s][c] *= gp[cb + i00] * w00 + gp[cb + i01] * w01 +
                      gp[cb + i10] * w10 + gp[cb + i11] * w11;
      }
    }
  }

#pragma unroll
  for (int s = 0; s < 4; ++s)
#pragma unroll
    for (int c = 0; c < 4; ++c)
      fl[pg][s * 32 + sub * 4 + c] = feat[s][c];
  __syncthreads();

  const int p = t & 63;
  const int g = __builtin_amdgcn_readfirstlane(t >> 6);

  const float* w0c = P.w0 + g * 8;
  float part[8];
#pragma unroll
  for (int jj = 0; jj < 8; ++jj) part[jj] = 0.0f;
#pragma unroll 16
  for (int k = 0; k < 128; ++k) {
    const float f = fl[p][k];
#pragma unroll
    for (int jj = 0; jj < 8; ++jj)
      part[jj] = fmaf(f, w0c[(size_t)k * 64 + jj], part[jj]);
  }
  __syncthreads();
#pragma unroll
  for (int jj = 0; jj < 8; ++jj)
    fl[p][g * 8 + jj] = fmaxf(part[jj], 0.0f);
  __syncthreads();

  const float* w1c = P.w1 + g * 8;
  float h1[8];
#pragma unroll
  for (int jj = 0; jj < 8; ++jj) h1[jj] = 0.0f;
#pragma unroll 16
  for (int k = 0; k < 64; ++k) {
    const float a = fl[p][k];
#pragma unroll
    for (int jj = 0; jj < 8; ++jj)
      h1[jj] = fmaf(a, w1c[(size_t)k * 64 + jj], h1[jj]);
  }

  const float* w2c = P.w2 + g * 8;
  float o = 0.0f;
#pragma unroll
  for (int jj = 0; jj < 8; ++jj)
    o = fmaf(fmaxf(h1[jj], 0.0f), w2c[jj], o);

  __syncthreads();
  ((float*)fl)[g * 64 + p] = o;
  __syncthreads();

  if (t < 64) {
    const int Po = blk0 + t;
    if (Po < P.N) {
      const float* f0 = (const float*)fl;
      float r = 0.0f;
#pragma unroll
      for (int j = 0; j < 8; ++j) r += f0[j * 64 + t];
      P.out[Po] = r;
    }
  }
}

extern "C" void kernel_launch(void* const* d_in, const int* in_sizes, int n_in,
                              void* d_out, int out_size, void* d_ws, size_t ws_size,
                              hipStream_t stream) {
  KParams P;
  P.x = (const float*)d_in[0];
  P.w0 = (const float*)d_in[13];
  P.w1 = (const float*)d_in[14];
  P.w2 = (const float*)d_in[15];
  P.out = (float*)d_out;
  const int N = in_sizes[0] / 3;
  P.N = N;
  P.xs = nullptr;
  P.sidx = nullptr;

  size_t need = 0;
  for (int s = 0; s < 4; ++s) {
    const size_t R = (size_t)(128 << s);
    need += 3ull * 32ull * R * R * sizeof(ushort_t);
  }
  const size_t walign = (need + 255) & ~(size_t)255;
  const size_t wbytes = (size_t)(64 * 128 + 64 * 64) * sizeof(ushort_t);
  const size_t cntoff = (walign + wbytes + 255) & ~(size_t)255;
  const size_t cntbytes = (size_t)NBUCKET * 4;
  const size_t doneoff = cntoff + cntbytes;           // 4B (zeroed w/ cnt)
  const size_t bsumoff = doneoff + 256;               // 256 u32
  const size_t sidxoff = (bsumoff + 1024 + 255) & ~(size_t)255;
  const size_t xsoff = (sidxoff + (size_t)N * 4 + 255) & ~(size_t)255;
  const size_t total_sorted = xsoff + (size_t)N * 12;

  const int nblk = (N + 63) / 64;
  const int pblk = (N + 255) / 256;
  if (ws_size >= walign + wbytes) {
    ushort_t* w = (ushort_t*)d_ws;
    TPA tpa;
    size_t off = 0;
    for (int s = 0; s < 4; ++s) {
      const int R = 128 << s;
      const int RR = R * R;
      for (int pl = 0; pl < 3; ++pl) {
        tpa.src[s * 3 + pl] = (const float*)d_in[1 + s * 3 + pl];
        tpa.dst[s * 3 + pl] = w + off;
        P.g[s * 3 + pl] = w + off;
        off += (size_t)32 * RR;
      }
    }
    ushort_t* w0T = (ushort_t*)((char*)d_ws + walign);
    ushort_t* w1T = w0T + 64 * 128;
    P.w0T = w0T;
    P.w1T = w1T;

    if (ws_size >= total_sorted) {
      uint_t* cnt = (uint_t*)((char*)d_ws + cntoff);
      uint_t* done = (uint_t*)((char*)d_ws + doneoff);
      uint_t* bsum = (uint_t*)((char*)d_ws + bsumoff);
      int* sidx = (int*)((char*)d_ws + sidxoff);
      float* xs = (float*)((char*)d_ws + xsoff);
      hipMemsetAsync(cnt, 0, cntbytes + 256, stream);  // cnt + done
      front_transpose_hist<<<NTRANSP + pblk, 256, 0, stream>>>(tpa, P.x, cnt, N);
      sort_scan_prepw<<<256, 1024, 0, stream>>>(cnt, bsum, done, P.w0, P.w1,
                                                w0T, w1T);
      sort_scatter<<<pblk, 256, 0, stream>>>(P.x, cnt, bsum, sidx, xs, N);
      P.xs = xs;
      P.sidx = sidx;
      kplanes_fused_mfma<true><<<nblk, 512, 0, stream>>>(P);
    } else {
      front_transpose_hist<<<NTRANSP, 256, 0, stream>>>(tpa, P.x, nullptr, N);
      prep_weights<<<1, 256, 0, stream>>>(P.w0, P.w1, w0T, w1T);
      kplanes_fused_mfma<false><<<nblk, 512, 0, stream>>>(P);
    }
  } else {
    for (int k = 0; k < 12; ++k) P.g[k] = (const void*)d_in[1 + k];
    P.w0T = nullptr;
    P.w1T = nullptr;
    kplanes_fused_scalar<<<nblk, 512, 0, stream>>>(P);
  }
}

// Round 12
// 615.742 us; speedup vs baseline: 1.1255x; 1.1255x over previous
//
#include <hip/hip_runtime.h>
#include <cstddef>

// K-Planes field eval: 4 scales x 3 planes bilinear sample (32ch), 3-way
// product per scale -> 128 feats -> MLP 128->64->64->1 (ReLU, bias-free).
//
// R12 strategy: R10 config (best: 637us) + two isolated front-end wins:
//  - transpose vectorized (2x float4 in, 1x uint4 out; 12 -> 3 mem insts)
//  - 5-bit Morton hist merged into transpose grid (one launch saved,
//      atomics hide in transpose tail); key16 cached for scatter
//  - scanA(32x1024) + scanB+weight-prep + key16 scatter = R10 exactly
//  - fused kernel = R10 byte-identical (depth-2 pipeline, (512,6), MFMA MLP)

typedef unsigned short ushort_t;
typedef unsigned int uint_t;
typedef __bf16 bf16x8 __attribute__((ext_vector_type(8)));
typedef float f32x4 __attribute__((ext_vector_type(4)));

#define NBUCKET 32768
#define NTRANSP 65280  // 21760 tiles x 3 planes

struct KParams {
  const float* x;
  const void* g[12];
  const float* w0;
  const float* w1;
  const float* w2;
  const ushort_t* w0T;  // [64 n][128 k] bf16
  const ushort_t* w1T;  // [64 n][64 k]  bf16
  const float* xs;      // sorted points [N][3]
  const int* sidx;      // sorted -> original index
  float* out;
  int N;
};

struct TPA {
  const float* src[12];
  ushort_t* dst[12];
};

__device__ __forceinline__ ushort_t f32_to_bf16_rne(float f) {
  uint_t u = __float_as_uint(f);
  u = (u + 0x7FFFu + ((u >> 16) & 1u)) >> 16;
  return (ushort_t)u;
}

__device__ __forceinline__ uint_t spread5(uint_t v) {
  return (v & 1u) | ((v & 2u) << 2) | ((v & 4u) << 4) | ((v & 8u) << 6) |
         ((v & 16u) << 8);
}
__device__ __forceinline__ uint_t morton_key(const float* __restrict__ x,
                                             int i) {
  const float a = x[3 * i + 0];
  const float b = x[3 * i + 1];
  const float c = x[3 * i + 2];
  const uint_t ua = (uint_t)fminf(fmaxf((a + 1.0f) * 16.0f, 0.0f), 31.0f);
  const uint_t ub = (uint_t)fminf(fmaxf((b + 1.0f) * 16.0f, 0.0f), 31.0f);
  const uint_t uc = (uint_t)fminf(fmaxf((c + 1.0f) * 16.0f, 0.0f), 31.0f);
  return spread5(ua) | (spread5(ub) << 1) | (spread5(uc) << 2);
}

// blocks [0,NTRANSP): transpose [32][RR] f32 -> [RR][32] bf16 (vectorized)
// blocks [NTRANSP,...): Morton histogram + key16 cache
__global__ __launch_bounds__(256) void front_transpose_hist(
    TPA tp, const float* __restrict__ x, uint_t* __restrict__ cnt,
    ushort_t* __restrict__ key16, int N) {
  const int b = blockIdx.x;
  const int t = threadIdx.x;
  if (b >= NTRANSP) {
    const int i = (b - NTRANSP) * 256 + t;
    if (i < N) {
      const uint_t k = morton_key(x, i);
      key16[i] = (ushort_t)k;
      atomicAdd(&cnt[k], 1u);
    }
    return;
  }
  const int v = b / 3;
  const int pl = b - v * 3;
  int s, tile;
  if (v < 256) { s = 0; tile = v; }
  else if (v < 1280) { s = 1; tile = v - 256; }
  else if (v < 5376) { s = 2; tile = v - 1280; }
  else { s = 3; tile = v - 5376; }
  const int RR = 16384 << (2 * s);
  const int k = s * 3 + pl;
  const float* __restrict__ in = tp.src[k];
  ushort_t* __restrict__ out = tp.dst[k];

  __shared__ float tile_s[32][68];  // stride 68 dw: rows 16B-aligned
  const int p0 = tile * 64;
  // read: 512 float4 (2/thread), coalesced rows
#pragma unroll
  for (int it = 0; it < 2; ++it) {
    const int idx = it * 256 + t;
    const int row = idx >> 4;
    const int qc = idx & 15;
    const float4 vv = *(const float4*)(in + (size_t)row * RR + p0 + qc * 4);
    *(float4*)&tile_s[row][qc * 4] = vv;
  }
  __syncthreads();
  // write: 256 uint4 (1/thread), coalesced
  const int pos = t >> 2;  // 0..63
  const int cq = t & 3;    // channels [cq*8, cq*8+8)
  uint4 dv;
  {
    uint_t d[4];
#pragma unroll
    for (int h = 0; h < 4; ++h) {
      const uint_t lo = f32_to_bf16_rne(tile_s[cq * 8 + 2 * h + 0][pos]);
      const uint_t hi = f32_to_bf16_rne(tile_s[cq * 8 + 2 * h + 1][pos]);
      d[h] = lo | (hi << 16);
    }
    dv.x = d[0]; dv.y = d[1]; dv.z = d[2]; dv.w = d[3];
  }
  *(uint4*)((uint_t*)out + (size_t)(p0 + pos) * 16 + cq * 4) = dv;
}

// standalone weight prep (non-sorted fallback path)
__global__ __launch_bounds__(256) void prep_weights(
    const float* __restrict__ w0, const float* __restrict__ w1,
    ushort_t* __restrict__ w0T, ushort_t* __restrict__ w1T) {
  const int t = threadIdx.x;
  for (int i = t; i < 128 * 64; i += 256) {
    const int k = i >> 6, n = i & 63;
    w0T[n * 128 + k] = f32_to_bf16_rne(w0[i]);
  }
  for (int i = t; i < 64 * 64; i += 256) {
    const int k = i >> 6, n = i & 63;
    w1T[n * 64 + k] = f32_to_bf16_rne(w1[i]);
  }
}

// block-local exclusive scan of 1024 buckets; block totals -> bsum
__global__ __launch_bounds__(1024) void sort_scanA(uint_t* __restrict__ cnt,
                                                   uint_t* __restrict__ bsum) {
  __shared__ uint_t s[1024];
  const int t = threadIdx.x;
  const int idx = blockIdx.x * 1024 + t;
  const uint_t v = cnt[idx];
  s[t] = v;
  __syncthreads();
  for (int off = 1; off < 1024; off <<= 1) {
    uint_t u = 0;
    if (t >= off) u = s[t - off];
    __syncthreads();
    s[t] += u;
    __syncthreads();
  }
  cnt[idx] = s[t] - v;  // local exclusive
  if (t == 1023) bsum[blockIdx.x] = s[t];
}

// 32-elem exclusive scan of bsum (thread 0) + weight prep (all threads)
__global__ __launch_bounds__(256) void sort_scanB_prepw(
    uint_t* __restrict__ bsum, const float* __restrict__ w0,
    const float* __restrict__ w1, ushort_t* __restrict__ w0T,
    ushort_t* __restrict__ w1T) {
  const int t = threadIdx.x;
  if (t == 0) {
    uint_t run = 0;
#pragma unroll
    for (int i = 0; i < 32; ++i) {
      const uint_t c = bsum[i];
      bsum[i] = run;
      run += c;
    }
  }
  for (int i = t; i < 128 * 64; i += 256) {
    const int k = i >> 6, n = i & 63;
    w0T[n * 128 + k] = f32_to_bf16_rne(w0[i]);
  }
  for (int i = t; i < 64 * 64; i += 256) {
    const int k = i >> 6, n = i & 63;
    w1T[n * 64 + k] = f32_to_bf16_rne(w1[i]);
  }
}

__global__ __launch_bounds__(256) void sort_scatter(
    const float* __restrict__ x, const ushort_t* __restrict__ key16,
    uint_t* __restrict__ cnt, const uint_t* __restrict__ bsum,
    int* __restrict__ sidx, float* __restrict__ xs, int N) {
  const int i = blockIdx.x * 256 + threadIdx.x;
  if (i >= N) return;
  const uint_t key = key16[i];
  const uint_t pos = atomicAdd(&cnt[key], 1u) + bsum[key >> 10];
  sidx[pos] = i;
  xs[3 * pos + 0] = x[3 * i + 0];
  xs[3 * pos + 1] = x[3 * i + 1];
  xs[3 * pos + 2] = x[3 * i + 2];
}

// ---------------- fused sample + MFMA MLP (R10, unchanged) ----------------
template <bool SORTED>
__global__ __launch_bounds__(512, 6) void kplanes_fused_mfma(KParams P) {
  __shared__ float arena[8704];
  int4* o4s = (int4*)arena;
  float* wxs = arena + 3072;
  float* wys = arena + 3840;
  uint_t* feat32 = (uint_t*)(arena + 4608);
  float* px = arena + 4608;

  const int t = threadIdx.x;

  int bid = blockIdx.x;
  if (SORTED) {
    const int nblk = gridDim.x;
    const int q = nblk >> 3, r = nblk & 7;
    const int xcd = bid & 7, idx = bid >> 3;
    bid = (xcd < r ? xcd * (q + 1) : r * (q + 1) + (xcd - r) * q) + idx;
  }
  const int blk0 = bid * 64;

  if (SORTED) {
    if (t < 192) {
      int idx = blk0 * 3 + t;
      if (idx >= 3 * P.N) idx = 3 * P.N - 3 + (t % 3);
      px[t] = P.xs[idx];
    }
  } else {
    if (t < 192) {
      const int p = t / 3, e = t - p * 3;
      int Pi = blk0 + p;
      if (Pi >= P.N) Pi = P.N - 1;
      px[t] = P.x[3 * Pi + e];
    }
  }
  __syncthreads();

  for (int task = t; task < 768; task += 512) {
    const int pt = task & 63;
    const int sm = task >> 6;
    const int pl = sm >> 2;
    const int s = sm & 3;
    const float cx = (pl == 2) ? px[pt * 3 + 1] : px[pt * 3 + 0];
    const float cy = (pl == 0) ? px[pt * 3 + 1] : px[pt * 3 + 2];
    const int R = 128 << s;
    const float Rm1 = (float)(R - 1);
    const float u = fminf(fmaxf((cx + 1.0f) * 0.5f * Rm1, 0.0f), Rm1);
    const float v = fminf(fmaxf((cy + 1.0f) * 0.5f * Rm1, 0.0f), Rm1);
    const float fx0 = floorf(u), fy0 = floorf(v);
    const int x0 = (int)fx0, y0 = (int)fy0;
    const int x1 = min(x0 + 1, R - 1), y1 = min(y0 + 1, R - 1);
    int4 o4;
    o4.x = y0 * R + x0;
    o4.y = y0 * R + x1;
    o4.z = y1 * R + x0;
    o4.w = y1 * R + x1;
    o4s[task] = o4;
    wxs[task] = u - fx0;
    wys[task] = v - fy0;
  }
  __syncthreads();

  const int pt = t >> 3;
  const int q = t & 7;
  const int cg = q & 3;
  const int sh = q >> 2;
  uint_t* prow = feat32 + pt * 64;
  const int wxor = (pt & 7) << 2;

#define CBASE(st) (((((st) % 3) * 4) + (2 * ((st) / 3) + sh)) * 64 + pt)
#define GIDX(st) ((2 * ((st) / 3) + sh) * 3 + ((st) % 3))
#define ISSUE(O, GP, QA, QB, QC, QD)                              \
  QA = *(const uint4*)((GP) + (size_t)(O).x * 32 + cg * 8);       \
  QB = *(const uint4*)((GP) + (size_t)(O).y * 32 + cg * 8);       \
  QC = *(const uint4*)((GP) + (size_t)(O).z * 32 + cg * 8);       \
  QD = *(const uint4*)((GP) + (size_t)(O).w * 32 + cg * 8);
#define CH2(dA, dB, dC, dD, i0, i1)                                \
  {                                                                \
    float rl = __uint_as_float((dD) << 16) * w11;                  \
    rl = fmaf(__uint_as_float((dC) << 16), w10, rl);               \
    rl = fmaf(__uint_as_float((dB) << 16), w01, rl);               \
    rl = fmaf(__uint_as_float((dA) << 16), w00, rl);               \
    f[i0] *= rl;                                                   \
    float rh = __uint_as_float((dD)&0xFFFF0000u) * w11;            \
    rh = fmaf(__uint_as_float((dC)&0xFFFF0000u), w10, rh);         \
    rh = fmaf(__uint_as_float((dB)&0xFFFF0000u), w01, rh);         \
    rh = fmaf(__uint_as_float((dA)&0xFFFF0000u), w00, rh);         \
    f[i1] *= rh;                                                   \
  }

  {
    uint4 A, B, C, D, A2, B2, C2, D2;
    float wx_c, wy_c, wx_n, wy_n;
    float f[8];

    {
      const int b_ = CBASE(0);
      const int4 o = o4s[b_];
      wx_c = wxs[b_];
      wy_c = wys[b_];
      const ushort_t* gp = (const ushort_t*)P.g[GIDX(0)];
      ISSUE(o, gp, A, B, C, D)
    }

#pragma unroll
    for (int st = 0; st < 6; ++st) {
      if (st < 5) {
        const int b_ = CBASE(st + 1);
        const int4 o = o4s[b_];
        wx_n = wxs[b_];
        wy_n = wys[b_];
        const ushort_t* gp = (const ushort_t*)P.g[GIDX(st + 1)];
        ISSUE(o, gp, A2, B2, C2, D2)
      }
      if ((st % 3) == 0) {
#pragma unroll
        for (int c = 0; c < 8; ++c) f[c] = 1.0f;
      }
      {
        const float w11 = wx_c * wy_c;
        const float w10 = wy_c - w11;
        const float w01 = wx_c - w11;
        const float w00 = 1.0f - wx_c - w10;
        CH2(A.x, B.x, C.x, D.x, 0, 1)
        CH2(A.y, B.y, C.y, D.y, 2, 3)
        CH2(A.z, B.z, C.z, D.z, 4, 5)
        CH2(A.w, B.w, C.w, D.w, 6, 7)
      }
      if ((st % 3) == 2) {
        const int s = 2 * (st / 3) + sh;
        uint_t d0, d1, d2, d3;
        asm("v_cvt_pk_bf16_f32 %0, %1, %2" : "=v"(d0) : "v"(f[0]), "v"(f[1]));
        asm("v_cvt_pk_bf16_f32 %0, %1, %2" : "=v"(d1) : "v"(f[2]), "v"(f[3]));
        asm("v_cvt_pk_bf16_f32 %0, %1, %2" : "=v"(d2) : "v"(f[4]), "v"(f[5]));
        asm("v_cvt_pk_bf16_f32 %0, %1, %2" : "=v"(d3) : "v"(f[6]), "v"(f[7]));
        uint4 dv;
        dv.x = d0; dv.y = d1; dv.z = d2; dv.w = d3;
        *(uint4*)(prow + ((s * 16 + cg * 4) ^ wxor)) = dv;
      }
      A = A2; B = B2; C = C2; D = D2;
      wx_c = wx_n; wy_c = wy_n;
    }
  }
#undef CBASE
#undef GIDX
#undef ISSUE
#undef CH2
  __syncthreads();

  ushort_t* lds_h = (ushort_t*)arena;
  float(*oparts)[64] = (float(*)[64])(arena + 2048);

  const int w = __builtin_amdgcn_readfirstlane(t >> 6);
  const int mt = w & 3;
  const int nt0 = (w >> 2) << 1;
  const int ln = t & 15;
  const int lq = (t >> 4) & 3;
  const int arow = mt * 16 + ln;

  const uint_t* farow = feat32 + arow * 64;
  const int axor = (arow & 7) << 2;
  f32x4 acc0a = {0.f, 0.f, 0.f, 0.f}, acc0b = {0.f, 0.f, 0.f, 0.f};
  const ushort_t* w0a = P.w0T + (nt0 * 16 + ln) * 128 + lq * 8;
  const ushort_t* w0b = w0a + 16 * 128;
#pragma unroll
  for (int kt = 0; kt < 4; ++kt) {
    const bf16x8 aF = *(const bf16x8*)(farow + ((kt * 16 + lq * 4) ^ axor));
    const bf16x8 bFa = *(const bf16x8*)(w0a + kt * 32);
    const bf16x8 bFb = *(const bf16x8*)(w0b + kt * 32);
    acc0a = __builtin_amdgcn_mfma_f32_16x16x32_bf16(aF, bFa, acc0a, 0, 0, 0);
    acc0b = __builtin_amdgcn_mfma_f32_16x16x32_bf16(aF, bFb, acc0b, 0, 0, 0);
  }

#pragma unroll
  for (int i = 0; i < 2; ++i) {
    const f32x4 a = i ? acc0b : acc0a;
    const int col = (nt0 + i) * 16 + ln;
#pragma unroll
    for (int jj = 0; jj < 4; ++jj) {
      const float v = fmaxf(a[jj], 0.0f);
      uint_t dv;
      asm("v_cvt_pk_bf16_f32 %0, %1, %2" : "=v"(dv) : "v"(v), "v"(v));
      const int r = mt * 16 + lq * 4 + jj;
      lds_h[r * 64 + (col ^ ((r & 7) << 3))] = (ushort_t)dv;
    }
  }
  __syncthreads();

  const ushort_t* hrow = lds_h + arow * 64;
  const int hxor = (arow & 7) << 3;
  f32x4 acc1a = {0.f, 0.f, 0.f, 0.f}, acc1b = {0.f, 0.f, 0.f, 0.f};
  const ushort_t* w1a = P.w1T + (nt0 * 16 + ln) * 64 + lq * 8;
  const ushort_t* w1b = w1a + 16 * 64;
#pragma unroll
  for (int kt = 0; kt < 2; ++kt) {
    const bf16x8 aF = *(const bf16x8*)(hrow + ((kt * 32 + lq * 8) ^ hxor));
    const bf16x8 bFa = *(const bf16x8*)(w1a + kt * 32);
    const bf16x8 bFb = *(const bf16x8*)(w1b + kt * 32);
    acc1a = __builtin_amdgcn_mfma_f32_16x16x32_bf16(aF, bFa, acc1a, 0, 0, 0);
    acc1b = __builtin_amdgcn_mfma_f32_16x16x32_bf16(aF, bFb, acc1b, 0, 0, 0);
  }

  const float w2a = P.w2[nt0 * 16 + ln];
  const float w2b = P.w2[(nt0 + 1) * 16 + ln];
  float part[4];
#pragma unroll
  for (int jj = 0; jj < 4; ++jj)
    part[jj] = fmaxf(acc1a[jj], 0.f) * w2a + fmaxf(acc1b[jj], 0.f) * w2b;
#pragma unroll
  for (int jj = 0; jj < 4; ++jj) {
    part[jj] += __shfl_xor(part[jj], 1);
    part[jj] += __shfl_xor(part[jj], 2);
    part[jj] += __shfl_xor(part[jj], 4);
    part[jj] += __shfl_xor(part[jj], 8);
  }
  if (ln == 0) {
#pragma unroll
    for (int jj = 0; jj < 4; ++jj)
      oparts[w >> 2][mt * 16 + lq * 4 + jj] = part[jj];
  }
  __syncthreads();

  if (t < 64) {
    const int Po = blk0 + t;
    if (Po < P.N) {
      const float r = oparts[0][t] + oparts[1][t];
      if (SORTED)
        P.out[P.sidx[Po]] = r;
      else
        P.out[Po] = r;
    }
  }
}

// fallback (ws too small): f32 [C,H,W] grids, scalar MLP
__global__ __launch_bounds__(512, 8) void kplanes_fused_scalar(KParams P) {
  __shared__ float fl[64][130];
  const int t = threadIdx.x;
  const int pg = t >> 3;
  const int sub = t & 7;
  const int blk0 = blockIdx.x * 64;

  int Pi = blk0 + pg;
  if (Pi >= P.N) Pi = P.N - 1;
  const float c0 = P.x[3 * Pi + 0];
  const float c1 = P.x[3 * Pi + 1];
  const float c2 = P.x[3 * Pi + 2];

  float feat[4][4];
#pragma unroll
  for (int s = 0; s < 4; ++s)
#pragma unroll
    for (int c = 0; c < 4; ++c) feat[s][c] = 1.0f;

#pragma unroll
  for (int s = 0; s < 4; ++s) {
    const int R = 128 << s;
    const int RR = R * R;
#pragma unroll
    for (int pl = 0; pl < 3; ++pl) {
      const float cx = (pl == 2) ? c1 : c0;
      const float cy = (pl == 0) ? c1 : c2;
      const float Rm1 = (float)(R - 1);
      const float u = fminf(fmaxf((cx + 1.0f) * 0.5f * Rm1, 0.0f), Rm1);
      const float v = fminf(fmaxf((cy + 1.0f) * 0.5f * Rm1, 0.0f), Rm1);
      const float fx0 = floorf(u), fy0 = floorf(v);
      const float wx = u - fx0, wy = v - fy0;
      const int x0 = (int)fx0, y0 = (int)fy0;
      const int x1 = min(x0 + 1, R - 1), y1 = min(y0 + 1, R - 1);
      const float w11 = wx * wy;
      const float w10 = wy - w11;
      const float w01 = wx - w11;
      const float w00 = 1.0f - wx - w10;
      const float* gp = (const float*)P.g[s * 3 + pl];
      const int i00 = y0 * R + x0, i01 = y0 * R + x1;
      const int i10 = y1 * R + x0, i11 = y1 * R + x1;
#pragma unroll
      for (int c = 0; c < 4; ++c) {
        const size_t cb = (size_t)(sub * 4 + c) * RR;
        feat[s][c] *= gp[cb + i00] * w00 + gp[cb + i01] * w01 +
                      gp[cb + i10] * w10 + gp[cb + i11] * w11;
      }
    }
  }

#pragma unroll
  for (int s = 0; s < 4; ++s)
#pragma unroll
    for (int c = 0; c < 4; ++c)
      fl[pg][s * 32 + sub * 4 + c] = feat[s][c];
  __syncthreads();

  const int p = t & 63;
  const int g = __builtin_amdgcn_readfirstlane(t >> 6);

  const float* w0c = P.w0 + g * 8;
  float part[8];
#pragma unroll
  for (int jj = 0; jj < 8; ++jj) part[jj] = 0.0f;
#pragma unroll 16
  for (int k = 0; k < 128; ++k) {
    const float f = fl[p][k];
#pragma unroll
    for (int jj = 0; jj < 8; ++jj)
      part[jj] = fmaf(f, w0c[(size_t)k * 64 + jj], part[jj]);
  }
  __syncthreads();
#pragma unroll
  for (int jj = 0; jj < 8; ++jj)
    fl[p][g * 8 + jj] = fmaxf(part[jj], 0.0f);
  __syncthreads();

  const float* w1c = P.w1 + g * 8;
  float h1[8];
#pragma unroll
  for (int jj = 0; jj < 8; ++jj) h1[jj] = 0.0f;
#pragma unroll 16
  for (int k = 0; k < 64; ++k) {
    const float a = fl[p][k];
#pragma unroll
    for (int jj = 0; jj < 8; ++jj)
      h1[jj] = fmaf(a, w1c[(size_t)k * 64 + jj], h1[jj]);
  }

  const float* w2c = P.w2 + g * 8;
  float o = 0.0f;
#pragma unroll
  for (int jj = 0; jj < 8; ++jj)
    o = fmaf(fmaxf(h1[jj], 0.0f), w2c[jj], o);

  __syncthreads();
  ((float*)fl)[g * 64 + p] = o;
  __syncthreads();

  if (t < 64) {
    const int Po = blk0 + t;
    if (Po < P.N) {
      const float* f0 = (const float*)fl;
      float r = 0.0f;
#pragma unroll
      for (int j = 0; j < 8; ++j) r += f0[j * 64 + t];
      P.out[Po] = r;
    }
  }
}

extern "C" void kernel_launch(void* const* d_in, const int* in_sizes, int n_in,
                              void* d_out, int out_size, void* d_ws, size_t ws_size,
                              hipStream_t stream) {
  KParams P;
  P.x = (const float*)d_in[0];
  P.w0 = (const float*)d_in[13];
  P.w1 = (const float*)d_in[14];
  P.w2 = (const float*)d_in[15];
  P.out = (float*)d_out;
  const int N = in_sizes[0] / 3;
  P.N = N;
  P.xs = nullptr;
  P.sidx = nullptr;

  size_t need = 0;
  for (int s = 0; s < 4; ++s) {
    const size_t R = (size_t)(128 << s);
    need += 3ull * 32ull * R * R * sizeof(ushort_t);
  }
  const size_t walign = (need + 255) & ~(size_t)255;
  const size_t wbytes = (size_t)(64 * 128 + 64 * 64) * sizeof(ushort_t);
  const size_t cntoff = (walign + wbytes + 255) & ~(size_t)255;
  const size_t cntbytes = (size_t)NBUCKET * 4;
  const size_t bsumoff = cntoff + cntbytes;          // 32 u32
  const size_t keyoff = (bsumoff + 128 + 255) & ~(size_t)255;
  const size_t sidxoff = (keyoff + (size_t)N * 2 + 255) & ~(size_t)255;
  const size_t xsoff = (sidxoff + (size_t)N * 4 + 255) & ~(size_t)255;
  const size_t total_sorted = xsoff + (size_t)N * 12;

  const int nblk = (N + 63) / 64;
  const int pblk = (N + 255) / 256;
  if (ws_size >= walign + wbytes) {
    ushort_t* w = (ushort_t*)d_ws;
    TPA tpa;
    size_t off = 0;
    for (int s = 0; s < 4; ++s) {
      const int R = 128 << s;
      const int RR = R * R;
      for (int pl = 0; pl < 3; ++pl) {
        tpa.src[s * 3 + pl] = (const float*)d_in[1 + s * 3 + pl];
        tpa.dst[s * 3 + pl] = w + off;
        P.g[s * 3 + pl] = w + off;
        off += (size_t)32 * RR;
      }
    }
    ushort_t* w0T = (ushort_t*)((char*)d_ws + walign);
    ushort_t* w1T = w0T + 64 * 128;
    P.w0T = w0T;
    P.w1T = w1T;

    if (ws_size >= total_sorted) {
      uint_t* cnt = (uint_t*)((char*)d_ws + cntoff);
      uint_t* bsum = (uint_t*)((char*)d_ws + bsumoff);
      ushort_t* key16 = (ushort_t*)((char*)d_ws + keyoff);
      int* sidx = (int*)((char*)d_ws + sidxoff);
      float* xs = (float*)((char*)d_ws + xsoff);
      hipMemsetAsync(cnt, 0, cntbytes, stream);
      front_transpose_hist<<<NTRANSP + pblk, 256, 0, stream>>>(tpa, P.x, cnt,
                                                               key16, N);
      sort_scanA<<<32, 1024, 0, stream>>>(cnt, bsum);
      sort_scanB_prepw<<<1, 256, 0, stream>>>(bsum, P.w0, P.w1, w0T, w1T);
      sort_scatter<<<pblk, 256, 0, stream>>>(P.x, key16, cnt, bsum, sidx, xs, N);
      P.xs = xs;
      P.sidx = sidx;
      kplanes_fused_mfma<true><<<nblk, 512, 0, stream>>>(P);
    } else {
      front_transpose_hist<<<NTRANSP, 256, 0, stream>>>(tpa, P.x, nullptr,
                                                        nullptr, N);
      prep_weights<<<1, 256, 0, stream>>>(P.w0, P.w1, w0T, w1T);
      kplanes_fused_mfma<false><<<nblk, 512, 0, stream>>>(P);
    }
  } else {
    for (int k = 0; k < 12; ++k) P.g[k] = (const void*)d_in[1 + k];
    P.w0T = nullptr;
    P.w1T = nullptr;
    kplanes_fused_scalar<<<nblk, 512, 0, stream>>>(P);
  }
}